// Round 9
// baseline (170.747 us; speedup 1.0000x reference)
//
#include <hip/hip_runtime.h>
#include <hip/hip_bf16.h>

#define EMB 1024
#define NH 16
#define HD 64
#define BATCH 2
#define SEQ 2048
#define MROWS (BATCH*SEQ)   // 4096
#define F3 (3*EMB)          // 3072

typedef __bf16 bf16;
typedef __attribute__((ext_vector_type(8))) __bf16 bf16x8;
typedef __attribute__((ext_vector_type(4))) __bf16 bf16x4;
typedef __attribute__((ext_vector_type(2))) __bf16 bf16x2;
typedef __attribute__((ext_vector_type(4))) float f32x4;
typedef __attribute__((ext_vector_type(16))) float f32x16;
typedef __attribute__((ext_vector_type(2))) unsigned int u32x2;

typedef const __attribute__((address_space(1))) void* gptr_t;
typedef __attribute__((address_space(3))) void* lptr_t;
#define GLDS16(g, l) __builtin_amdgcn_global_load_lds((gptr_t)(g), (lptr_t)(l), 16, 0, 0)

__device__ inline bf16 tobf(float f) {
    union { __hip_bfloat16 h; bf16 b; } cv;
    cv.h = __float2bfloat16(f);   // RNE
    return cv.b;
}

__device__ inline float fexp2(float x) {
#if __has_builtin(__builtin_amdgcn_exp2f)
    return __builtin_amdgcn_exp2f(x);
#else
    return exp2f(x);
#endif
}

// permlane32_swap: a' = [a_lo | b_lo], b' = [a_hi | b_hi]
__device__ inline void plswap(unsigned& a, unsigned& b) {
#if __has_builtin(__builtin_amdgcn_permlane32_swap)
    u32x2 r = __builtin_amdgcn_permlane32_swap(a, b, false, false);
    a = r[0]; b = r[1];
#else
    unsigned pa = (unsigned)__shfl_xor((int)a, 32, 64);
    unsigned pb = (unsigned)__shfl_xor((int)b, 32, 64);
    bool hi = (threadIdx.x & 32) != 0;
    unsigned na = hi ? pb : a;
    unsigned nb = hi ? b : pa;
    a = na; b = nb;
#endif
}
__device__ inline void plswapf(float& a, float& b) {
    unsigned ua = __builtin_bit_cast(unsigned, a), ub = __builtin_bit_cast(unsigned, b);
    plswap(ua, ub);
    a = __builtin_bit_cast(float, ua); b = __builtin_bit_cast(float, ub);
}
__device__ inline unsigned pack2(float x, float y) {   // bf16(x) low | bf16(y) high
    bf16x2 t; t[0] = (bf16)x; t[1] = (bf16)y;
    return __builtin_bit_cast(unsigned, t);
}

// ---------------- fused fp32 -> bf16 conversion (x, w_qkv, w_out) ----------------
#define N1 (MROWS*EMB)
#define N2 (F3*EMB)
#define N3 (EMB*EMB)
__global__ __launch_bounds__(256) void cvt_all(const float* __restrict__ x,
                                               const float* __restrict__ wq,
                                               const float* __restrict__ wo,
                                               bf16* __restrict__ xb,
                                               bf16* __restrict__ wqb,
                                               bf16* __restrict__ wob) {
    int i = (blockIdx.x * 256 + threadIdx.x) * 4;
    const float* src;
    bf16* dst;
    int off;
    if (i < N1)           { src = x;  dst = xb;  off = i; }
    else if (i < N1 + N2) { src = wq; dst = wqb; off = i - N1; }
    else                  { src = wo; dst = wob; off = i - N1 - N2; }
    const float4 v = *reinterpret_cast<const float4*>(src + off);
    bf16x4 o;
    o[0] = tobf(v.x); o[1] = tobf(v.y); o[2] = tobf(v.z); o[3] = tobf(v.w);
    *reinterpret_cast<bf16x4*>(dst + off) = o;
}

// ================= GEMM1: 256x256 8-phase (m201 template, derived) =================
// qkv = x @ w_qkv^T, scatter to Q(scaled)/K/V^T.  BM=BN=256, BK=64, 512 thr (2Mx4N waves).
// Steady state: b1's tile (2it+1) is completed by CURRENT iter p1 (A-m0) / p2 (B-n1);
// prev iter p7/p8 staged B-n0/A-m1.  R6 bug: peeled last iter omitted p1/p2 stages ->
// tile 15 half-stale.  Fixed: peeled iter stages A-m0/B-n1 <- 15, drains vmcnt(0) at p4.
__global__ __launch_bounds__(512, 2) void gemm_qkv(const bf16* __restrict__ A,
                                                   const bf16* __restrict__ Bw,
                                                   bf16* __restrict__ qb,
                                                   bf16* __restrict__ kb,
                                                   bf16* __restrict__ vt) {
    extern __shared__ bf16 dsm[];                 // [2][256*64] A | [2][256*64] B
    bf16* Al = dsm;                               // + b*16384
    bf16* Bl = dsm + 32768;

    const int tid = threadIdx.x;
    const int w = tid >> 6, l = tid & 63;
    const int wm = w >> 2, wn = w & 3;
    const int m0 = blockIdx.y * 256, n0 = blockIdx.x * 256;

    // stage constants: wave-linear dest (row = base + l>>3, chunk = l&7), pre-swizzled src
    const int sc = ((l & 7) ^ (l >> 3)) * 8;      // src col-chunk elem offset
    const int lr = l >> 3;                        // dest row offset within 8-row stripe
    const int l15 = l & 15, l4 = l >> 4, l7 = l & 7;

    f32x4 acc[8][4];
#pragma unroll
    for (int i = 0; i < 8; ++i)
#pragma unroll
        for (int j = 0; j < 4; ++j) acc[i][j] = f32x4{0.f, 0.f, 0.f, 0.f};

    bf16x8 Af[4][2], Bf[2][2];

    // ---- stage macros: 2 x GLDS16 each ----
#define STA(bb, mh, ct)                                                                  \
    do {                                                                                 \
        int rs_ = (mh) * 64 + w * 8;                                                     \
        GLDS16(A + (size_t)(m0 + rs_ + lr) * 1024 + (ct) * 64 + sc, (lptr_t)&Al[(bb) * 16384 + rs_ * 64]);          \
        GLDS16(A + (size_t)(m0 + 128 + rs_ + lr) * 1024 + (ct) * 64 + sc, (lptr_t)&Al[(bb) * 16384 + (128 + rs_) * 64]); \
    } while (0)
#define STB(bb, nh, ct)                                                                  \
    do {                                                                                 \
        int r1_ = (w >> 2) * 64 + (nh) * 32 + (w & 3) * 8;                               \
        int r2_ = r1_ + 128;                                                             \
        GLDS16(Bw + (size_t)(n0 + r1_ + lr) * 1024 + (ct) * 64 + sc, (lptr_t)&Bl[(bb) * 16384 + r1_ * 64]); \
        GLDS16(Bw + (size_t)(n0 + r2_ + lr) * 1024 + (ct) * 64 + sc, (lptr_t)&Bl[(bb) * 16384 + r2_ * 64]); \
    } while (0)
    // ---- frag loads (swizzled ds_read_b128) ----
#define LDA(bb, mh)                                                                      \
    do {                                                                                 \
        _Pragma("unroll") for (int mi = 0; mi < 4; ++mi)                                 \
        _Pragma("unroll") for (int ks = 0; ks < 2; ++ks)                                 \
            Af[mi][ks] = *reinterpret_cast<const bf16x8*>(                               \
                &Al[(bb) * 16384 + (wm * 128 + (mh) * 64 + mi * 16 + l15) * 64 +         \
                    (((ks * 4 + l4) ^ l7) * 8)]);                                        \
    } while (0)
#define LDB(bb, nh)                                                                      \
    do {                                                                                 \
        _Pragma("unroll") for (int ni = 0; ni < 2; ++ni)                                 \
        _Pragma("unroll") for (int ks = 0; ks < 2; ++ks)                                 \
            Bf[ni][ks] = *reinterpret_cast<const bf16x8*>(                               \
                &Bl[(bb) * 16384 + (wn * 64 + (nh) * 32 + ni * 16 + l15) * 64 +          \
                    (((ks * 4 + l4) ^ l7) * 8)]);                                        \
    } while (0)
#define MM(mh, nh)                                                                       \
    do {                                                                                 \
        __builtin_amdgcn_s_setprio(1);                                                   \
        _Pragma("unroll") for (int mi = 0; mi < 4; ++mi)                                 \
        _Pragma("unroll") for (int ni = 0; ni < 2; ++ni)                                 \
        _Pragma("unroll") for (int ks = 0; ks < 2; ++ks)                                 \
            acc[(mh) * 4 + mi][(nh) * 2 + ni] = __builtin_amdgcn_mfma_f32_16x16x32_bf16( \
                Af[mi][ks], Bf[ni][ks], acc[(mh) * 4 + mi][(nh) * 2 + ni], 0, 0, 0);     \
        __builtin_amdgcn_s_setprio(0);                                                   \
    } while (0)
#define PH_TAIL()                                                                        \
    __builtin_amdgcn_s_barrier();                                                        \
    asm volatile("s_waitcnt lgkmcnt(0)" ::: "memory");                                   \
    __builtin_amdgcn_sched_barrier(0)
#define PH_END() __builtin_amdgcn_s_barrier()

    // ---- prologue: tile0 -> buf0 (all 4 regions), tile1 -> buf1 (B-n0, A-m1) ----
    STA(0, 0, 0); STA(0, 1, 0); STB(0, 0, 0); STB(0, 1, 0);
    STB(1, 0, 1); STA(1, 1, 1);
    asm volatile("s_waitcnt vmcnt(4)" ::: "memory");   // tile0's 8 loads landed
    __builtin_amdgcn_s_barrier();

    // ---- main loop: iters 0..6 steady (tiles 2it, 2it+1), iter 7 peeled ----
#pragma unroll 1
    for (int it = 0; it < 7; ++it) {
        const int t1 = 2 * it + 1;
        // p1: read b0 (A-m0, B-n0); stage b1.A-m0 <- t1
        LDA(0, 0); LDB(0, 0);
        __builtin_amdgcn_sched_barrier(0);
        STA(1, 0, t1);
        PH_TAIL(); MM(0, 0); PH_END();
        // p2: read b0 A-m1; stage b1.B-n1 <- t1
        LDA(0, 1);
        __builtin_amdgcn_sched_barrier(0);
        STB(1, 1, t1);
        PH_TAIL(); MM(1, 0); PH_END();
        // p3: read b0 B-n1; stage b0.B-n0 <- t0+2
        LDB(0, 1);
        __builtin_amdgcn_sched_barrier(0);
        STB(0, 0, t1 + 1);
        PH_TAIL(); MM(1, 1); PH_END();
        // p4: reload b0 A-m0; stage b0.A-m1 <- t0+2; vmcnt(4)
        LDA(0, 0);
        __builtin_amdgcn_sched_barrier(0);
        STA(0, 1, t1 + 1);
        asm volatile("s_waitcnt vmcnt(4)" ::: "memory");
        PH_TAIL(); MM(0, 1); PH_END();
        // p5: read b1 (A-m0, B-n0); stage b0.A-m0 <- t0+2
        LDA(1, 0); LDB(1, 0);
        __builtin_amdgcn_sched_barrier(0);
        STA(0, 0, t1 + 1);
        PH_TAIL(); MM(0, 0); PH_END();
        // p6: read b1 A-m1; stage b0.B-n1 <- t0+2
        LDA(1, 1);
        __builtin_amdgcn_sched_barrier(0);
        STB(0, 1, t1 + 1);
        PH_TAIL(); MM(1, 0); PH_END();
        // p7: read b1 B-n1; stage b1.B-n0 <- t1+2
        LDB(1, 1);
        __builtin_amdgcn_sched_barrier(0);
        STB(1, 0, t1 + 2);
        PH_TAIL(); MM(1, 1); PH_END();
        // p8: reload b1 A-m0; stage b1.A-m1 <- t1+2; vmcnt(4)
        LDA(1, 0);
        __builtin_amdgcn_sched_barrier(0);
        STA(1, 1, t1 + 2);
        asm volatile("s_waitcnt vmcnt(4)" ::: "memory");
        PH_TAIL(); MM(0, 1); PH_END();
    }
    // ---- peeled last iter (tiles 14 in b0, 15 in b1) ----
    // MUST still stage b1.A-m0 / b1.B-n1 <- tile 15 (steady state does this at p1/p2).
    {
        LDA(0, 0); LDB(0, 0);
        __builtin_amdgcn_sched_barrier(0);
        STA(1, 0, 15);
        PH_TAIL(); MM(0, 0); PH_END();
        LDA(0, 1);
        __builtin_amdgcn_sched_barrier(0);
        STB(1, 1, 15);
        PH_TAIL(); MM(1, 0); PH_END();
        LDB(0, 1);
        PH_TAIL(); MM(1, 1); PH_END();
        LDA(0, 0);
        asm volatile("s_waitcnt vmcnt(0)" ::: "memory");   // drain: tile15 fully landed
        PH_TAIL(); MM(0, 1); PH_END();
        LDA(1, 0); LDB(1, 0);
        PH_TAIL(); MM(0, 0); PH_END();
        LDA(1, 1);
        PH_TAIL(); MM(1, 0); PH_END();
        LDB(1, 1);
        PH_TAIL(); MM(1, 1); PH_END();
        LDA(1, 0);
        PH_TAIL(); MM(0, 1); PH_END();
    }

    // ---- epilogue: scatter into Q (x scale), K, V^T ----
    const int which = (n0 + wn * 64) >> 10;        // wave-uniform
#pragma unroll
    for (int mf = 0; mf < 8; ++mf) {
#pragma unroll
        for (int nf = 0; nf < 4; ++nf) {
            int fcol = n0 + wn * 64 + nf * 16 + l15;
            int h = (fcol >> 6) & 15, d = fcol & 63;
            int mbase = m0 + wm * 128 + mf * 16 + l4 * 4;
            int b = mbase >> 11, s = mbase & 2047;
            int bh = b * NH + h;
            if (which == 2) {
                bf16x4 vv;
#pragma unroll
                for (int jj = 0; jj < 4; ++jj) vv[jj] = tobf(acc[mf][nf][jj]);
                *reinterpret_cast<bf16x4*>(&vt[((size_t)bh * HD + d) * SEQ + s]) = vv;
            } else if (which == 0) {
#pragma unroll
                for (int jj = 0; jj < 4; ++jj)
                    qb[((size_t)bh * SEQ + s + jj) * HD + d] = tobf(acc[mf][nf][jj] * 0.180336881f);
            } else {
#pragma unroll
                for (int jj = 0; jj < 4; ++jj)
                    kb[((size_t)bh * SEQ + s + jj) * HD + d] = tobf(acc[mf][nf][jj]);
            }
        }
    }
#undef STA
#undef STB
#undef LDA
#undef LDB
#undef MM
#undef PH_TAIL
#undef PH_END
}

// ---------------- Flash attention (causal), swapped-operand 32x32 MFMA ----------------
__global__ __launch_bounds__(512, 4) void attn_kernel(const bf16* __restrict__ qb,
                                                      const bf16* __restrict__ kb,
                                                      const bf16* __restrict__ vt,
                                                      bf16* __restrict__ ao) {
    __shared__ alignas(16) char SM[69632];
    bf16 (*Kl)[4096] = (bf16 (*)[4096])SM;             // [4][64*64]  32KB
    bf16 (*Vl)[4096] = (bf16 (*)[4096])(SM + 32768);   // [4][64*64]  32KB
    float* Msh = (float*)(SM + 65536);                 // [8][64]      2KB
    float* Rsh = (float*)(SM + 67584);                 // [8][64]      2KB
    float* Osh = (float*)SM;                           // combine reuse 32KB

    const int tid = threadIdx.x, w = tid >> 6, l = tid & 63;
    const int hi = l >> 5;
    const int qg = w & 3, kg = w >> 2;
    const int h = (int)(blockIdx.x >> 5);
    const int qt = (h < 8) ? (15 - h) : (h - 8);       // complementary pairing
    const int bh = blockIdx.x & 31;
    const int q0 = qt * 128;
    const bf16* Qp = qb + (size_t)bh * SEQ * HD;
    const bf16* Kp = kb + (size_t)bh * SEQ * HD;
    const bf16* Vp = vt + (size_t)bh * HD * SEQ;

    const int qa = q0 + qg * 32 + (l & 31);            // this lane's q row
    bf16x8 qf[4];
#pragma unroll
    for (int kk = 0; kk < 4; ++kk)
        qf[kk] = *reinterpret_cast<const bf16x8*>(&Qp[(size_t)qa * HD + kk * 16 + hi * 8]);

    f32x16 o[2];
#pragma unroll
    for (int t = 0; t < 2; ++t)
#pragma unroll
        for (int r = 0; r < 16; ++r) o[t][r] = 0.f;
    float m = -__builtin_inff(), rs = 0.f;

    const int sc = ((l & 7) ^ (l >> 3)) * 8;           // pre-swizzled source chunk

#define STAGE(itp)                                                                  \
    do {                                                                            \
        int j_ = 2 * (itp) + kg;                                                    \
        int slot_ = j_ & 3;                                                         \
        int kv0_ = j_ * 64;                                                         \
        int r0_ = qg * 16 + (l >> 3);                                               \
        GLDS16(Kp + (size_t)(kv0_ + r0_) * HD + sc, &Kl[slot_][(qg * 16) * 64]);    \
        GLDS16(Kp + (size_t)(kv0_ + r0_ + 8) * HD + sc, &Kl[slot_][(qg * 16 + 8) * 64]); \
        GLDS16(Vp + (size_t)r0_ * SEQ + kv0_ + sc, &Vl[slot_][(qg * 16) * 64]);     \
        GLDS16(Vp + (size_t)(r0_ + 8) * SEQ + kv0_ + sc, &Vl[slot_][(qg * 16 + 8) * 64]); \
    } while (0)

    STAGE(0);
    __syncthreads();

    const int qminw = q0 + qg * 32;
    const int qmaxw = qminw + 31;

    for (int it = 0; it <= qt; ++it) {
        if (it < qt) STAGE(it + 1);                    // prefetch tiles 2it+2, 2it+3
        const int j = 2 * it + kg;
        if (j * 64 <= qmaxw) {                         // wave-uniform causal skip
            const int slot = j & 3;
            // --- S^T = K_tile . Q^T ---
            f32x16 st[2];
            __builtin_amdgcn_s_setprio(1);
#pragma unroll
            for (int t = 0; t < 2; ++t) {
#pragma unroll
                for (int r = 0; r < 16; ++r) st[t][r] = 0.f;
                int row = t * 32 + (l & 31);
                int rsw = (row & 7) << 3;
#pragma unroll
                for (int kk = 0; kk < 4; ++kk) {
                    bf16x8 kf = *reinterpret_cast<const bf16x8*>(
                        &Kl[slot][row * 64 + ((kk * 16 + hi * 8) ^ rsw)]);
                    st[t] = __builtin_amdgcn_mfma_f32_32x32x16_bf16(kf, qf[kk], st[t], 0, 0, 0);
                }
            }
            __builtin_amdgcn_s_setprio(0);
            // --- causal mask ---
            if (j * 64 + 63 > qminw) {
#pragma unroll
                for (int t = 0; t < 2; ++t)
#pragma unroll
                    for (int r = 0; r < 16; ++r) {
                        int kv = j * 64 + t * 32 + 8 * (r >> 2) + 4 * hi + (r & 3);
                        if (kv > qa) st[t][r] = -__builtin_inff();
                    }
            }
            // --- tile max: depth-4 tree + one swap ---
            float red[8];
#pragma unroll
            for (int r = 0; r < 8; ++r)
                red[r] = fmaxf(fmaxf(st[0][r], st[0][r + 8]), fmaxf(st[1][r], st[1][r + 8]));
            float pm = fmaxf(fmaxf(fmaxf(red[0], red[1]), fmaxf(red[2], red[3])),
                             fmaxf(fmaxf(red[4], red[5]), fmaxf(red[6], red[7])));
            float pa_ = pm, pb_ = pm;
            plswapf(pa_, pb_);
            pm = fmaxf(pa_, pb_);
            // --- defer-max (THR=8 in log2 domain) ---
            if (!__all(pm <= m + 8.f)) {
                float mn = fmaxf(m, pm);
                float al = fexp2(m - mn);
#pragma unroll
                for (int t = 0; t < 2; ++t)
#pragma unroll
                    for (int r = 0; r < 16; ++r) o[t][r] *= al;
                rs *= al;
                m = mn;
            }
            // --- P = exp2(S^T - m), per-lane row-sum ---
#pragma unroll
            for (int t = 0; t < 2; ++t)
#pragma unroll
                for (int r = 0; r < 16; ++r) {
                    float p = fexp2(st[t][r] - m);
                    st[t][r] = p;
                    rs += p;
                }
            // --- P^T fragments (pack2 + permlane32_swap), PV ---
#pragma unroll
            for (int t = 0; t < 2; ++t) {
                unsigned Ag[4], Bg[4];
#pragma unroll
                for (int g = 0; g < 4; ++g) {
                    Ag[g] = pack2(st[t][4 * g + 0], st[t][4 * g + 1]);
                    Bg[g] = pack2(st[t][4 * g + 2], st[t][4 * g + 3]);
                }
                __builtin_amdgcn_s_setprio(1);
#pragma unroll
                for (int k2 = 0; k2 < 2; ++k2) {
                    unsigned w0 = Ag[2 * k2], w2 = Ag[2 * k2 + 1];
                    plswap(w0, w2);
                    unsigned w1 = Bg[2 * k2], w3 = Bg[2 * k2 + 1];
                    plswap(w1, w3);
                    union { unsigned u[4]; bf16x8 v; } pf;
                    pf.u[0] = w0; pf.u[1] = w1; pf.u[2] = w2; pf.u[3] = w3;
                    const int kk = 2 * t + k2;
#pragma unroll
                    for (int dt = 0; dt < 2; ++dt) {
                        int row = dt * 32 + (l & 31);
                        bf16x8 vf = *reinterpret_cast<const bf16x8*>(
                            &Vl[slot][row * 64 + ((kk * 16 + hi * 8) ^ ((row & 7) << 3))]);
                        o[dt] = __builtin_amdgcn_mfma_f32_32x32x16_bf16(vf, pf.v, o[dt], 0, 0, 0);
                    }
                }
                __builtin_amdgcn_s_setprio(0);
            }
        }
        __syncthreads();   // staged tiles complete (vmcnt0) + slot reuse safe
    }

    // --- combine the two kv-group states (partner waves w and w+4) ---
    float rlo = rs, rhi = rs;
    plswapf(rlo, rhi);
    const float rfull = rlo + rhi;                     // full row-sum for q = qa
    Msh[w * 64 + l] = m;
    Rsh[w * 64 + l] = rfull;
    if (kg == 1) {
        float* dst = Osh + (size_t)(qg * 64 + l) * 32; // 128B per lane
#pragma unroll
        for (int c = 0; c < 8; ++c) {                  // chunk c at swizzled slot
            f32x4 tch;
#pragma unroll
            for (int i = 0; i < 4; ++i) tch[i] = o[c >> 2][(c & 3) * 4 + i];
            *reinterpret_cast<f32x4*>(dst + (c ^ (l & 7)) * 4) = tch;
        }
    }
    __syncthreads();
    if (kg == 0) {
        const float mb = Msh[(w + 4) * 64 + l];
        const float rb = Rsh[(w + 4) * 64 + l];
        const float mstar = fmaxf(m, mb);
        const float sa = fexp2(m - mstar), sb = fexp2(mb - mstar);
        const float inv = 1.f / (rfull * sa + rb * sb);
        const float* src = Osh + (size_t)(qg * 64 + l) * 32;
        const int b = bh >> 4, hh = bh & 15;
#pragma unroll
        for (int c = 0; c < 8; ++c) {
            f32x4 ob = *reinterpret_cast<const f32x4*>(src + (c ^ (l & 7)) * 4);
            bf16x4 ov;
#pragma unroll
            for (int i = 0; i < 4; ++i)
                ov[i] = (bf16)((o[c >> 2][(c & 3) * 4 + i] * sa + ob[i] * sb) * inv);
            int d0 = (c >> 2) * 32 + 8 * (c & 3) + 4 * hi;
            *reinterpret_cast<bf16x4*>(&ao[((size_t)b * SEQ + qa) * EMB + hh * HD + d0]) = ov;
        }
    }
#undef STAGE
}

// ---------------- GEMM2: out = attn @ w_out^T + b_out (fp32 out) ----------------
// 64x128 (MxN) tiles -> 512 blocks = 2/CU.
__global__ __launch_bounds__(256) void gemm_out(const bf16* __restrict__ A,
                                                const bf16* __restrict__ Bw,
                                                float* __restrict__ out,
                                                const float* __restrict__ bias) {
    const int K = 1024;
    __shared__ alignas(16) bf16 Alds[64 * 32];
    __shared__ alignas(16) bf16 Blds[128 * 32];
    const int tid = threadIdx.x;
    const int w = tid >> 6, l = tid & 63;
    const int m0 = blockIdx.y * 64, n0 = blockIdx.x * 128;

    f32x4 acc[4][2];
#pragma unroll
    for (int mi = 0; mi < 4; ++mi)
#pragma unroll
        for (int ni = 0; ni < 2; ++ni)
            acc[mi][ni] = f32x4{0.f, 0.f, 0.f, 0.f};

    const int srow = l >> 2;
    const int scol = (l & 3) * 8;
    const bf16* Abase = A + (size_t)m0 * K;
    const bf16* Bbase = Bw + (size_t)n0 * K;

    for (int k0 = 0; k0 < K; k0 += 32) {
        GLDS16(Abase + (size_t)(w * 16 + srow) * K + k0 + scol, &Alds[w * 512]);
#pragma unroll
        for (int i = 0; i < 2; ++i) {
            int chunk = w * 2 + i;
            GLDS16(Bbase + (size_t)(chunk * 16 + srow) * K + k0 + scol, &Blds[chunk * 512]);
        }
        __syncthreads();
        bf16x8 af[4], bfr[2];
#pragma unroll
        for (int mi = 0; mi < 4; ++mi)
            af[mi] = *reinterpret_cast<const bf16x8*>(
                &Alds[(mi * 16 + (l & 15)) * 32 + (l >> 4) * 8]);
#pragma unroll
        for (int ni = 0; ni < 2; ++ni)
            bfr[ni] = *reinterpret_cast<const bf16x8*>(
                &Blds[(w * 32 + ni * 16 + (l & 15)) * 32 + (l >> 4) * 8]);
#pragma unroll
        for (int mi = 0; mi < 4; ++mi)
#pragma unroll
            for (int ni = 0; ni < 2; ++ni)
                acc[mi][ni] = __builtin_amdgcn_mfma_f32_16x16x32_bf16(
                    af[mi], bfr[ni], acc[mi][ni], 0, 0, 0);
        __syncthreads();
    }

#pragma unroll
    for (int mi = 0; mi < 4; ++mi) {
#pragma unroll
        for (int ni = 0; ni < 2; ++ni) {
            int fcol = n0 + w * 32 + ni * 16 + (l & 15);
            float bv = bias[fcol];
#pragma unroll
            for (int jj = 0; jj < 4; ++jj) {
                int m = m0 + mi * 16 + (l >> 4) * 4 + jj;
                out[(size_t)m * EMB + fcol] = acc[mi][ni][jj] + bv;
            }
        }
    }
}

// ---------------- launch ----------------
extern "C" void kernel_launch(void* const* d_in, const int* in_sizes, int n_in,
                              void* d_out, int out_size, void* d_ws, size_t ws_size,
                              hipStream_t stream) {
    const float* x     = (const float*)d_in[0];
    const float* w_qkv = (const float*)d_in[1];
    const float* w_out = (const float*)d_in[2];
    const float* b_out = (const float*)d_in[3];
    float* out = (float*)d_out;

    char* ws = (char*)d_ws;
    bf16* xb    = (bf16*)(ws);                       // 8 MB  [4096][1024]
    bf16* wqkvb = (bf16*)(ws + ((size_t)8 << 20));   // 6 MB  [3072][1024]
    bf16* woutb = (bf16*)(ws + ((size_t)14 << 20));  // 2 MB  [1024][1024]
    bf16* qb    = (bf16*)(ws + ((size_t)16 << 20));  // 8 MB  [32][2048][64] (scaled, log2e)
    bf16* kb    = (bf16*)(ws + ((size_t)24 << 20));  // 8 MB  [32][2048][64]
    bf16* vt    = (bf16*)(ws + ((size_t)32 << 20));  // 8 MB  [32][64][2048] (V^T)
    bf16* ab    = (bf16*)(ws + ((size_t)40 << 20));  // 8 MB  [4096][1024]

    hipFuncSetAttribute((const void*)gemm_qkv,
                        hipFuncAttributeMaxDynamicSharedMemorySize, 131072);

    cvt_all<<<(N1 + N2 + N3) / 1024, 256, 0, stream>>>(x, w_qkv, w_out, xb, wqkvb, woutb);
    gemm_qkv<<<dim3(F3 / 256, MROWS / 256), 512, 131072, stream>>>(xb, wqkvb, qb, kb, vt);
    attn_kernel<<<512, 512, 0, stream>>>(qb, kb, vt, ab);
    gemm_out<<<dim3(EMB / 128, MROWS / 64), 256, 0, stream>>>(ab, woutb, out, b_out);
}